// Round 7
// baseline (506.524 us; speedup 1.0000x reference)
//
#include <hip/hip_runtime.h>

#define NEG_SLOPE 0.2f

typedef __attribute__((ext_vector_type(8))) short bf16x8;
typedef __attribute__((ext_vector_type(4))) float f32x4;

__device__ __forceinline__ float bf2f(ushort u) {
  return __uint_as_float(((unsigned int)u) << 16);
}
__device__ __forceinline__ ushort f2bf(float f) {  // round-to-nearest-even
  unsigned int u = __float_as_uint(f);
  u += 0x7fff + ((u >> 16) & 1);
  return (ushort)(u >> 16);
}
__device__ __forceinline__ float lrelu(float e) { return e > 0.f ? e : NEG_SLOPE * e; }

__device__ __forceinline__ float wave_max64(float v) {
  for (int off = 32; off; off >>= 1) v = fmaxf(v, __shfl_xor(v, off));
  return v;
}
__device__ __forceinline__ float wave_sum64(float v) {
  for (int off = 32; off; off >>= 1) v += __shfl_xor(v, off);
  return v;
}

// ---------------- CSR build ----------------

__global__ void hist_k(const int* __restrict__ ei, int E, int E2, int* __restrict__ deg) {
  int i = blockIdx.x * 256 + threadIdx.x;
  if (i >= E2) return;
  int d = (i < E) ? ei[E + i] : (i - E);
  atomicAdd(&deg[d], 1);
}

__global__ void scan1_k(const int* __restrict__ deg, int* __restrict__ excl,
                        int* __restrict__ bsum, int N) {
  __shared__ int sm[256];
  int t = threadIdx.x;
  int base = blockIdx.x * 1024 + t * 4;
  int v0 = (base + 0 < N) ? deg[base + 0] : 0;
  int v1 = (base + 1 < N) ? deg[base + 1] : 0;
  int v2 = (base + 2 < N) ? deg[base + 2] : 0;
  int v3 = (base + 3 < N) ? deg[base + 3] : 0;
  int tsum = v0 + v1 + v2 + v3;
  sm[t] = tsum;
  __syncthreads();
  for (int off = 1; off < 256; off <<= 1) {
    int x = (t >= off) ? sm[t - off] : 0;
    __syncthreads();
    sm[t] += x;
    __syncthreads();
  }
  int run = sm[t] - tsum;
  if (base + 0 < N) excl[base + 0] = run; run += v0;
  if (base + 1 < N) excl[base + 1] = run; run += v1;
  if (base + 2 < N) excl[base + 2] = run; run += v2;
  if (base + 3 < N) excl[base + 3] = run;
  if (t == 255) bsum[blockIdx.x] = sm[255];
}

__global__ void scan2_k(int* __restrict__ bsum, int nb) {
  int t = threadIdx.x;
  int orig = (t < nb) ? bsum[t] : 0;
  int v = orig;
  for (int off = 1; off < 64; off <<= 1) {
    int x = __shfl_up(v, off);
    if (t >= off) v += x;
  }
  if (t < nb) bsum[t] = v - orig;
}

__global__ void scan3_k(const int* __restrict__ excl, const int* __restrict__ bsum,
                        int* __restrict__ rowptr, int* __restrict__ wptr, int N, int E2) {
  int i = blockIdx.x * 256 + threadIdx.x;
  if (i < N) {
    int r = excl[i] + bsum[i >> 10];
    rowptr[i] = r;
    wptr[i] = r;
  }
  if (i == N) rowptr[N] = E2;
}

__global__ void scatter_k(const int* __restrict__ ei, int E, int E2,
                          int* __restrict__ wptr, int* __restrict__ csr_src) {
  int i = blockIdx.x * 256 + threadIdx.x;
  if (i >= E2) return;
  int s, d;
  if (i < E) { s = ei[i]; d = ei[E + i]; }
  else       { s = d = i - E; }
  int pos = atomicAdd(&wptr[d], 1);
  csr_src[pos] = s;
}

// ---------------- conversions ----------------

__global__ void f2b_k(const float* __restrict__ in, ushort* __restrict__ out, int n4) {
  int i = blockIdx.x * 256 + threadIdx.x;
  if (i >= n4) return;
  float4 v = ((const float4*)in)[i];
  ushort4 o;
  o.x = f2bf(v.x); o.y = f2bf(v.y); o.z = f2bf(v.z); o.w = f2bf(v.w);
  ((ushort4*)out)[i] = o;
}

// all three weight transposes in one launch: W[K][Nc] f32 -> Wt[Nc][K] bf16
__global__ void wtrans3_k(const float* __restrict__ W1, const float* __restrict__ W2,
                          const float* __restrict__ W3, ushort* __restrict__ w1t,
                          ushort* __restrict__ w2t, ushort* __restrict__ w3t) {
  int z = blockIdx.z;
  const float* W = z == 0 ? W1 : z == 1 ? W2 : W3;
  ushort* Wt = z == 0 ? w1t : z == 1 ? w2t : w3t;
  int K = z == 0 ? 128 : 256;
  int Nc = z == 2 ? 64 : 256;
  int k = blockIdx.x * 16 + (threadIdx.x & 15);
  int n = blockIdx.y * 16 + (threadIdx.x >> 4);
  if (k < K && n < Nc) Wt[(size_t)n * K + k] = f2bf(W[(size_t)k * Nc + n]);
}

// ------- bf16 MFMA GEMM + fused attention coefficients -------
// C[M,N]=A[M,K]@B[K,N] (Bt[N][K] input). BM=128, BN=64, BK=64; 4 waves,
// wave w owns rows [bm+32w, bm+32w+32). Each BN=64 tile is one head h=bn/64;
// epilogue computes a_s[row*H+h] and a_d[row*H+h] via 16-lane shfl reduce.

__global__ __launch_bounds__(256) void gemm_att(const ushort* __restrict__ A,
                                                const ushort* __restrict__ Bt,
                                                ushort* __restrict__ C,
                                                const float* __restrict__ att_s,
                                                const float* __restrict__ att_d,
                                                float* __restrict__ a_s,
                                                float* __restrict__ a_d,
                                                int M, int N, int K, int H) {
  __shared__ ushort As[128][72];  // +8 pad -> 2-way (free) ds_read conflicts
  __shared__ ushort Bs[64][72];
  int tid = threadIdx.x;
  int w = tid >> 6, l = tid & 63;
  int bm = blockIdx.y * 128, bn = blockIdx.x * 64;
  int fr = l & 15, fg = l >> 4, fk = fg * 8;
  f32x4 acc[2][4];
#pragma unroll
  for (int ar = 0; ar < 2; ++ar)
#pragma unroll
    for (int nb = 0; nb < 4; ++nb) acc[ar][nb] = (f32x4){0.f, 0.f, 0.f, 0.f};
  for (int k0 = 0; k0 < K; k0 += 64) {
#pragma unroll
    for (int i = 0; i < 4; ++i) {  // A: 128 rows x 8 segs
      int s = tid + i * 256;
      int row = s >> 3, sc = (s & 7) * 8;
      bf16x8 v = {0, 0, 0, 0, 0, 0, 0, 0};
      if (bm + row < M) v = *(const bf16x8*)(A + (size_t)(bm + row) * K + k0 + sc);
      *(bf16x8*)&As[row][sc] = v;
    }
#pragma unroll
    for (int i = 0; i < 2; ++i) {  // B: 64 rows x 8 segs
      int s = tid + i * 256;
      int row = s >> 3, sc = (s & 7) * 8;
      bf16x8 v = *(const bf16x8*)(Bt + (size_t)(bn + row) * K + k0 + sc);
      *(bf16x8*)&Bs[row][sc] = v;
    }
    __syncthreads();
#pragma unroll
    for (int kk = 0; kk < 64; kk += 32) {
      bf16x8 a0 = *(bf16x8*)&As[32 * w + fr][kk + fk];
      bf16x8 a1 = *(bf16x8*)&As[32 * w + 16 + fr][kk + fk];
#pragma unroll
      for (int nb = 0; nb < 4; ++nb) {
        bf16x8 b = *(bf16x8*)&Bs[nb * 16 + fr][kk + fk];
        acc[0][nb] = __builtin_amdgcn_mfma_f32_16x16x32_bf16(a0, b, acc[0][nb], 0, 0, 0);
        acc[1][nb] = __builtin_amdgcn_mfma_f32_16x16x32_bf16(a1, b, acc[1][nb], 0, 0, 0);
      }
    }
    __syncthreads();
  }
  int h = bn >> 6;
  float asc[4], adc[4];
#pragma unroll
  for (int nb = 0; nb < 4; ++nb) {
    asc[nb] = att_s[h * 64 + nb * 16 + fr];
    adc[nb] = att_d[h * 64 + nb * 16 + fr];
  }
#pragma unroll
  for (int ar = 0; ar < 2; ++ar) {
#pragma unroll
    for (int r = 0; r < 4; ++r) {
      float vs = 0.f, vd = 0.f;
#pragma unroll
      for (int nb = 0; nb < 4; ++nb) {
        vs = fmaf(acc[ar][nb][r], asc[nb], vs);
        vd = fmaf(acc[ar][nb][r], adc[nb], vd);
      }
#pragma unroll
      for (int off = 1; off < 16; off <<= 1) {
        vs += __shfl_xor(vs, off);
        vd += __shfl_xor(vd, off);
      }
      int row = bm + 32 * w + 16 * ar + fg * 4 + r;
      if (fr == 0 && row < M) {
        a_s[(size_t)row * H + h] = vs;
        a_d[(size_t)row * H + h] = vd;
      }
    }
#pragma unroll
    for (int nb = 0; nb < 4; ++nb)
#pragma unroll
      for (int r = 0; r < 4; ++r) {
        int row = bm + 32 * w + 16 * ar + fg * 4 + r;
        if (row < M) C[(size_t)row * N + bn + nb * 16 + fr] = f2bf(acc[ar][nb][r]);
      }
  }
}

// ---------------- edge softmax weights (unnormalized) ----------------
// pass 1: gather a_s, stage raw e into alpha (sequential write), wave-max.
// pass 2: sequential re-read (own-XCD L2), exp, write back, sum.

template <int WPB>
__global__ __launch_bounds__(64 * WPB) void alpha4_k(
    const float4* __restrict__ a_s4, const float4* __restrict__ a_d4,
    const int* __restrict__ rowptr, const int* __restrict__ csr_src,
    float4* __restrict__ alpha, float4* __restrict__ invs, int N) {
  int w = threadIdx.x >> 6, l = threadIdx.x & 63;
  int n = blockIdx.x * WPB + w;
  if (n >= N) return;
  int beg = rowptr[n], end = rowptr[n + 1];
  float4 ad = a_d4[n];
  float m0 = -1e30f, m1 = -1e30f, m2 = -1e30f, m3 = -1e30f;
  for (int c0 = beg; c0 < end; c0 += 64) {
    int cnt = min(64, end - c0);
    float e0 = -1e30f, e1 = -1e30f, e2 = -1e30f, e3 = -1e30f;
    if (l < cnt) {
      float4 as = a_s4[csr_src[c0 + l]];
      e0 = lrelu(as.x + ad.x); e1 = lrelu(as.y + ad.y);
      e2 = lrelu(as.z + ad.z); e3 = lrelu(as.w + ad.w);
      alpha[c0 + l] = make_float4(e0, e1, e2, e3);
    }
    m0 = fmaxf(m0, wave_max64(e0));
    m1 = fmaxf(m1, wave_max64(e1));
    m2 = fmaxf(m2, wave_max64(e2));
    m3 = fmaxf(m3, wave_max64(e3));
  }
  float s0 = 0.f, s1 = 0.f, s2 = 0.f, s3 = 0.f;
  for (int c0 = beg; c0 < end; c0 += 64) {
    int cnt = min(64, end - c0);
    float p0 = 0.f, p1 = 0.f, p2 = 0.f, p3 = 0.f;
    if (l < cnt) {
      float4 e = alpha[c0 + l];
      p0 = __expf(e.x - m0); p1 = __expf(e.y - m1);
      p2 = __expf(e.z - m2); p3 = __expf(e.w - m3);
      alpha[c0 + l] = make_float4(p0, p1, p2, p3);
    }
    s0 += wave_sum64(p0); s1 += wave_sum64(p1);
    s2 += wave_sum64(p2); s3 += wave_sum64(p3);
  }
  if (l == 0) invs[n] = make_float4(1.f / s0, 1.f / s1, 1.f / s2, 1.f / s3);
}

template <int WPB>
__global__ __launch_bounds__(64 * WPB) void alpha1_k(
    const float* __restrict__ a_s, const float* __restrict__ a_d,
    const int* __restrict__ rowptr, const int* __restrict__ csr_src,
    float* __restrict__ alpha, float* __restrict__ invs, int N) {
  int w = threadIdx.x >> 6, l = threadIdx.x & 63;
  int n = blockIdx.x * WPB + w;
  if (n >= N) return;
  int beg = rowptr[n], end = rowptr[n + 1];
  float ad = a_d[n];
  float m = -1e30f;
  for (int c0 = beg; c0 < end; c0 += 64) {
    int cnt = min(64, end - c0);
    float e = -1e30f;
    if (l < cnt) {
      e = lrelu(a_s[csr_src[c0 + l]] + ad);
      alpha[c0 + l] = e;
    }
    m = fmaxf(m, wave_max64(e));
  }
  float s = 0.f;
  for (int c0 = beg; c0 < end; c0 += 64) {
    int cnt = min(64, end - c0);
    float p = 0.f;
    if (l < cnt) {
      p = __expf(alpha[c0 + l] - m);
      alpha[c0 + l] = p;
    }
    s += wave_sum64(p);
  }
  if (l == 0) invs[n] = 1.f / s;
}

// ---------------- aggregation, H=4: pure weighted gather, unroll x4 ----------------

template <int WPB, int ACT>
__global__ __launch_bounds__(64 * WPB) void agg4_k(
    const ushort* __restrict__ xw, const float4* __restrict__ alpha,
    const float4* __restrict__ invs, const int* __restrict__ rowptr,
    const int* __restrict__ csr_src, const float* __restrict__ bias,
    ushort* __restrict__ hout, int N) {
  __shared__ float pbuf[WPB][4][66];
  int w = threadIdx.x >> 6, l = threadIdx.x & 63;
  int n = blockIdx.x * WPB + w;
  if (n >= N) return;
  int h = l >> 4;
  int beg = rowptr[n], end = rowptr[n + 1];
  f32x4 a0 = {0.f, 0.f, 0.f, 0.f}, a1 = {0.f, 0.f, 0.f, 0.f};
  f32x4 a2 = {0.f, 0.f, 0.f, 0.f}, a3 = {0.f, 0.f, 0.f, 0.f};
  const ushort4* xw4 = (const ushort4*)xw;
  for (int c0 = beg; c0 < end; c0 += 64) {
    int cnt = min(64, end - c0);
    int sidx = 0;
    float4 p = make_float4(0.f, 0.f, 0.f, 0.f);
    if (l < cnt) {
      sidx = csr_src[c0 + l];
      p = alpha[c0 + l];
    }
    pbuf[w][0][l] = p.x; pbuf[w][1][l] = p.y;
    pbuf[w][2][l] = p.z; pbuf[w][3][l] = p.w;
    // single-wave LDS producer/consumer: in-order, no barrier
    int j = 0;
    for (; j + 4 <= cnt; j += 4) {
      int s0 = __builtin_amdgcn_readlane(sidx, j);
      int s1 = __builtin_amdgcn_readlane(sidx, j + 1);
      int s2 = __builtin_amdgcn_readlane(sidx, j + 2);
      int s3 = __builtin_amdgcn_readlane(sidx, j + 3);
      float p0 = pbuf[w][h][j], p1 = pbuf[w][h][j + 1];
      float p2 = pbuf[w][h][j + 2], p3 = pbuf[w][h][j + 3];
      ushort4 v0 = xw4[(size_t)s0 * 64 + l];
      ushort4 v1 = xw4[(size_t)s1 * 64 + l];
      ushort4 v2 = xw4[(size_t)s2 * 64 + l];
      ushort4 v3 = xw4[(size_t)s3 * 64 + l];
      a0[0] = fmaf(p0, bf2f(v0.x), a0[0]); a0[1] = fmaf(p0, bf2f(v0.y), a0[1]);
      a0[2] = fmaf(p0, bf2f(v0.z), a0[2]); a0[3] = fmaf(p0, bf2f(v0.w), a0[3]);
      a1[0] = fmaf(p1, bf2f(v1.x), a1[0]); a1[1] = fmaf(p1, bf2f(v1.y), a1[1]);
      a1[2] = fmaf(p1, bf2f(v1.z), a1[2]); a1[3] = fmaf(p1, bf2f(v1.w), a1[3]);
      a2[0] = fmaf(p2, bf2f(v2.x), a2[0]); a2[1] = fmaf(p2, bf2f(v2.y), a2[1]);
      a2[2] = fmaf(p2, bf2f(v2.z), a2[2]); a2[3] = fmaf(p2, bf2f(v2.w), a2[3]);
      a3[0] = fmaf(p3, bf2f(v3.x), a3[0]); a3[1] = fmaf(p3, bf2f(v3.y), a3[1]);
      a3[2] = fmaf(p3, bf2f(v3.z), a3[2]); a3[3] = fmaf(p3, bf2f(v3.w), a3[3]);
    }
    for (; j < cnt; ++j) {
      int sj = __builtin_amdgcn_readlane(sidx, j);
      float pj = pbuf[w][h][j];
      ushort4 v = xw4[(size_t)sj * 64 + l];
      a0[0] = fmaf(pj, bf2f(v.x), a0[0]); a0[1] = fmaf(pj, bf2f(v.y), a0[1]);
      a0[2] = fmaf(pj, bf2f(v.z), a0[2]); a0[3] = fmaf(pj, bf2f(v.w), a0[3]);
    }
  }
  float4 iv = invs[n];
  float inv = h == 0 ? iv.x : h == 1 ? iv.y : h == 2 ? iv.z : iv.w;
  float4 bv = ((const float4*)bias)[l];
  float o0 = ((a0[0] + a1[0]) + (a2[0] + a3[0])) * inv + bv.x;
  float o1 = ((a0[1] + a1[1]) + (a2[1] + a3[1])) * inv + bv.y;
  float o2 = ((a0[2] + a1[2]) + (a2[2] + a3[2])) * inv + bv.z;
  float o3 = ((a0[3] + a1[3]) + (a2[3] + a3[3])) * inv + bv.w;
  if (ACT) {
    o0 = o0 > 0.f ? o0 : __expf(o0) - 1.f;
    o1 = o1 > 0.f ? o1 : __expf(o1) - 1.f;
    o2 = o2 > 0.f ? o2 : __expf(o2) - 1.f;
    o3 = o3 > 0.f ? o3 : __expf(o3) - 1.f;
  }
  ushort4 ov;
  ov.x = f2bf(o0); ov.y = f2bf(o1); ov.z = f2bf(o2); ov.w = f2bf(o3);
  ((ushort4*)(hout + (size_t)n * 256))[l] = ov;
}

// ---------------- aggregation, H=1 (layer 3): 4 edges/iter ----------------

template <int WPB>
__global__ __launch_bounds__(64 * WPB) void agg1_k(
    const ushort* __restrict__ xw, const float* __restrict__ alpha,
    const float* __restrict__ invs, const int* __restrict__ rowptr,
    const int* __restrict__ csr_src, const float* __restrict__ bias,
    float* __restrict__ hout, int N) {
  __shared__ float pbuf[WPB][64];
  __shared__ int sbuf[WPB][64];
  int w = threadIdx.x >> 6, l = threadIdx.x & 63;
  int n = blockIdx.x * WPB + w;
  if (n >= N) return;
  int g = l >> 4, q = l & 15;
  int beg = rowptr[n], end = rowptr[n + 1];
  f32x4 acc = {0.f, 0.f, 0.f, 0.f};
  const ushort4* xw4 = (const ushort4*)xw;
  for (int c0 = beg; c0 < end; c0 += 64) {
    int cnt = min(64, end - c0);
    int sidx = 0;
    float p = 0.f;
    if (l < cnt) {
      sidx = csr_src[c0 + l];
      p = alpha[c0 + l];
    }
    pbuf[w][l] = p;
    sbuf[w][l] = sidx;
    for (int j = 0; j < cnt; j += 4) {
      int jj = j + g;
      bool ok = jj < cnt;
      int idx = ok ? jj : 0;
      float pj = ok ? pbuf[w][idx] : 0.f;
      int sj = sbuf[w][idx];
      ushort4 v = xw4[(size_t)sj * 16 + q];
      acc[0] = fmaf(pj, bf2f(v.x), acc[0]);
      acc[1] = fmaf(pj, bf2f(v.y), acc[1]);
      acc[2] = fmaf(pj, bf2f(v.z), acc[2]);
      acc[3] = fmaf(pj, bf2f(v.w), acc[3]);
    }
  }
#pragma unroll
  for (int i = 0; i < 4; ++i) {
    acc[i] += __shfl_xor(acc[i], 16);
    acc[i] += __shfl_xor(acc[i], 32);
  }
  float inv = invs[n];
  float4 bv = ((const float4*)bias)[q];
  float4 o;
  o.x = acc[0] * inv + bv.x;
  o.y = acc[1] * inv + bv.y;
  o.z = acc[2] * inv + bv.z;
  o.w = acc[3] * inv + bv.w;
  if (g == 0) ((float4*)(hout + (size_t)n * 64))[q] = o;
}

// ---------------- final mean over nodes + classifier ----------------

__global__ void reduce_mean_k(const float* __restrict__ h3, float* __restrict__ g, int N) {
  __shared__ float sm[4][64];
  int w = threadIdx.x >> 6;
  int lane = threadIdx.x & 63;
  float acc = 0.f;
  for (int n = blockIdx.x * 4 + w; n < N; n += gridDim.x * 4)
    acc += h3[(size_t)n * 64 + lane];
  sm[w][lane] = acc;
  __syncthreads();
  if (w == 0) {
    float t = sm[0][lane] + sm[1][lane] + sm[2][lane] + sm[3][lane];
    atomicAdd(&g[lane], t);
  }
}

__global__ void final_k(const float* __restrict__ g, const float* __restrict__ Wc,
                        const float* __restrict__ bc, float* __restrict__ out, int N) {
  int lane = threadIdx.x;  // 64
  float gc = g[lane] / (float)N;
  for (int j = 0; j < 10; ++j) {
    float v = gc * Wc[lane * 10 + j];
    for (int off = 32; off; off >>= 1) v += __shfl_down(v, off);
    if (lane == 0) out[j] = v + bc[j];
  }
}

// ---------------- launch ----------------

extern "C" void kernel_launch(void* const* d_in, const int* in_sizes, int n_in,
                              void* d_out, int out_size, void* d_ws, size_t ws_size,
                              hipStream_t stream) {
  const float* x   = (const float*)d_in[0];
  const int*   ei  = (const int*)d_in[1];
  const float* W1  = (const float*)d_in[2];
  const float* as1 = (const float*)d_in[3];
  const float* ad1 = (const float*)d_in[4];
  const float* b1  = (const float*)d_in[5];
  const float* W2  = (const float*)d_in[6];
  const float* as2 = (const float*)d_in[7];
  const float* ad2 = (const float*)d_in[8];
  const float* b2  = (const float*)d_in[9];
  const float* W3  = (const float*)d_in[10];
  const float* as3 = (const float*)d_in[11];
  const float* ad3 = (const float*)d_in[12];
  const float* b3  = (const float*)d_in[13];
  const float* Wc  = (const float*)d_in[14];
  const float* bc  = (const float*)d_in[15];
  float* out = (float*)d_out;

  int N = in_sizes[0] / 128;
  int E = in_sizes[1] / 2;
  int E2 = E + N;

  char* w = (char*)d_ws;
  auto alloc = [&](size_t bytes) {
    char* p = w;
    w += (bytes + 255) & ~(size_t)255;
    return p;
  };
  ushort* xb   = (ushort*)alloc((size_t)N * 128 * 2);  // reused as h3f (layer 3, f32[N][64])
  float*  h3f  = (float*)xb;
  ushort* xwb  = (ushort*)alloc((size_t)N * 256 * 2);
  ushort* hb   = (ushort*)alloc((size_t)N * 256 * 2);
  float*  alph = (float*)alloc((size_t)E2 * 4 * 4);
  float*  invs = (float*)alloc((size_t)N * 4 * 4);
  ushort* w1t  = (ushort*)alloc((size_t)256 * 128 * 2);
  ushort* w2t  = (ushort*)alloc((size_t)256 * 256 * 2);
  ushort* w3t  = (ushort*)alloc((size_t)64 * 256 * 2);
  float*  a_s  = (float*)alloc((size_t)N * 4 * 4);
  float*  a_d  = (float*)alloc((size_t)N * 4 * 4);
  int*   deg    = (int*)alloc((size_t)N * 4);
  int*   excl   = (int*)alloc((size_t)N * 4);
  int*   bsum   = (int*)alloc(64 * 4);
  int*   rowptr = (int*)alloc((size_t)(N + 1) * 4);
  int*   wptr   = (int*)alloc((size_t)N * 4);
  int*   csr    = (int*)alloc((size_t)E2 * 4);
  float* g      = (float*)alloc(64 * 4);

  hipMemsetAsync(deg, 0, (size_t)N * 4, stream);
  hipMemsetAsync(g, 0, 64 * 4, stream);

  // conversions
  f2b_k<<<(N * 128 / 4 + 255) / 256, 256, 0, stream>>>(x, xb, N * 128 / 4);
  wtrans3_k<<<dim3(16, 16, 3), 256, 0, stream>>>(W1, W2, W3, w1t, w2t, w3t);

  // CSR
  int gE2 = (E2 + 255) / 256;
  hist_k<<<gE2, 256, 0, stream>>>(ei, E, E2, deg);
  int nb = (N + 1023) / 1024;
  scan1_k<<<nb, 256, 0, stream>>>(deg, excl, bsum, N);
  scan2_k<<<1, 64, 0, stream>>>(bsum, nb);
  scan3_k<<<(N + 256) / 256, 256, 0, stream>>>(excl, bsum, rowptr, wptr, N, E2);
  scatter_k<<<gE2, 256, 0, stream>>>(ei, E, E2, wptr, csr);

  int mb = (N + 127) / 128;
  int nwb = (N + 3) / 4;
  // layer 1
  gemm_att<<<dim3(4, mb), 256, 0, stream>>>(xb, w1t, xwb, as1, ad1, a_s, a_d, N, 256, 128, 4);
  alpha4_k<4><<<nwb, 256, 0, stream>>>((const float4*)a_s, (const float4*)a_d, rowptr, csr,
                                       (float4*)alph, (float4*)invs, N);
  agg4_k<4, 1><<<nwb, 256, 0, stream>>>(xwb, (const float4*)alph, (const float4*)invs,
                                        rowptr, csr, b1, hb, N);
  // layer 2
  gemm_att<<<dim3(4, mb), 256, 0, stream>>>(hb, w2t, xwb, as2, ad2, a_s, a_d, N, 256, 256, 4);
  alpha4_k<4><<<nwb, 256, 0, stream>>>((const float4*)a_s, (const float4*)a_d, rowptr, csr,
                                       (float4*)alph, (float4*)invs, N);
  agg4_k<4, 1><<<nwb, 256, 0, stream>>>(xwb, (const float4*)alph, (const float4*)invs,
                                        rowptr, csr, b2, hb, N);
  // layer 3 (single head)
  gemm_att<<<dim3(1, mb), 256, 0, stream>>>(hb, w3t, xwb, as3, ad3, a_s, a_d, N, 64, 256, 1);
  alpha1_k<4><<<nwb, 256, 0, stream>>>(a_s, a_d, rowptr, csr, alph, invs, N);
  agg1_k<4><<<nwb, 256, 0, stream>>>(xwb, alph, invs, rowptr, csr, b3, h3f, N);

  reduce_mean_k<<<256, 256, 0, stream>>>(h3f, g, N);
  final_k<<<1, 64, 0, stream>>>(g, Wc, bc, out, N);
}

// Round 8
// 415.469 us; speedup vs baseline: 1.2192x; 1.2192x over previous
//
#include <hip/hip_runtime.h>

#define NEG_SLOPE 0.2f

typedef __attribute__((ext_vector_type(8))) short bf16x8;
typedef __attribute__((ext_vector_type(4))) float f32x4;

__device__ __forceinline__ float bf2f(ushort u) {
  return __uint_as_float(((unsigned int)u) << 16);
}
__device__ __forceinline__ ushort f2bf(float f) {  // round-to-nearest-even
  unsigned int u = __float_as_uint(f);
  u += 0x7fff + ((u >> 16) & 1);
  return (ushort)(u >> 16);
}
__device__ __forceinline__ float lrelu(float e) { return e > 0.f ? e : NEG_SLOPE * e; }

__device__ __forceinline__ float wave_max64(float v) {
  for (int off = 32; off; off >>= 1) v = fmaxf(v, __shfl_xor(v, off));
  return v;
}
__device__ __forceinline__ float wave_sum64(float v) {
  for (int off = 32; off; off >>= 1) v += __shfl_xor(v, off);
  return v;
}

// ---------------- CSR build ----------------
// hist + per-edge rank (returning atomic lives here; hidden by TLP)
__global__ void histoff_k(const int* __restrict__ ei, int E, int E2,
                          int* __restrict__ deg, int* __restrict__ eoff) {
  int i = blockIdx.x * 256 + threadIdx.x;
  if (i >= E2) return;
  int d = (i < E) ? ei[E + i] : (i - E);
  eoff[i] = atomicAdd(&deg[d], 1);
}

__global__ void scan1_k(const int* __restrict__ deg, int* __restrict__ excl,
                        int* __restrict__ bsum, int N) {
  __shared__ int sm[256];
  int t = threadIdx.x;
  int base = blockIdx.x * 1024 + t * 4;
  int v0 = (base + 0 < N) ? deg[base + 0] : 0;
  int v1 = (base + 1 < N) ? deg[base + 1] : 0;
  int v2 = (base + 2 < N) ? deg[base + 2] : 0;
  int v3 = (base + 3 < N) ? deg[base + 3] : 0;
  int tsum = v0 + v1 + v2 + v3;
  sm[t] = tsum;
  __syncthreads();
  for (int off = 1; off < 256; off <<= 1) {
    int x = (t >= off) ? sm[t - off] : 0;
    __syncthreads();
    sm[t] += x;
    __syncthreads();
  }
  int run = sm[t] - tsum;
  if (base + 0 < N) excl[base + 0] = run; run += v0;
  if (base + 1 < N) excl[base + 1] = run; run += v1;
  if (base + 2 < N) excl[base + 2] = run; run += v2;
  if (base + 3 < N) excl[base + 3] = run;
  if (t == 255) bsum[blockIdx.x] = sm[255];
}

__global__ void scan2_k(int* __restrict__ bsum, int nb) {
  int t = threadIdx.x;
  int orig = (t < nb) ? bsum[t] : 0;
  int v = orig;
  for (int off = 1; off < 64; off <<= 1) {
    int x = __shfl_up(v, off);
    if (t >= off) v += x;
  }
  if (t < nb) bsum[t] = v - orig;
}

__global__ void scan3_k(const int* __restrict__ excl, const int* __restrict__ bsum,
                        int* __restrict__ rowptr, int N, int E2) {
  int i = blockIdx.x * 256 + threadIdx.x;
  if (i < N) rowptr[i] = excl[i] + bsum[i >> 10];
  if (i == N) rowptr[N] = E2;
}

// atomic-free scatter: pos known from rowptr + eoff
__global__ void scatter_k(const int* __restrict__ ei, int E, int E2,
                          const int* __restrict__ rowptr, const int* __restrict__ eoff,
                          int* __restrict__ csr_src) {
  int i = blockIdx.x * 256 + threadIdx.x;
  if (i >= E2) return;
  int s, d;
  if (i < E) { s = ei[i]; d = ei[E + i]; }
  else       { s = d = i - E; }
  csr_src[rowptr[d] + eoff[i]] = s;
}

// ---------------- conversions ----------------

__global__ void f2b_k(const float* __restrict__ in, ushort* __restrict__ out, int n4) {
  int i = blockIdx.x * 256 + threadIdx.x;
  if (i >= n4) return;
  float4 v = ((const float4*)in)[i];
  ushort4 o;
  o.x = f2bf(v.x); o.y = f2bf(v.y); o.z = f2bf(v.z); o.w = f2bf(v.w);
  ((ushort4*)out)[i] = o;
}

// all three weight transposes in one launch: W[K][Nc] f32 -> Wt[Nc][K] bf16
__global__ void wtrans3_k(const float* __restrict__ W1, const float* __restrict__ W2,
                          const float* __restrict__ W3, ushort* __restrict__ w1t,
                          ushort* __restrict__ w2t, ushort* __restrict__ w3t) {
  int z = blockIdx.z;
  const float* W = z == 0 ? W1 : z == 1 ? W2 : W3;
  ushort* Wt = z == 0 ? w1t : z == 1 ? w2t : w3t;
  int K = z == 0 ? 128 : 256;
  int Nc = z == 2 ? 64 : 256;
  int k = blockIdx.x * 16 + (threadIdx.x & 15);
  int n = blockIdx.y * 16 + (threadIdx.x >> 4);
  if (k < K && n < Nc) Wt[(size_t)n * K + k] = f2bf(W[(size_t)k * Nc + n]);
}

// ------- bf16 MFMA GEMM + fused attention coefficients -------

__global__ __launch_bounds__(256) void gemm_att(const ushort* __restrict__ A,
                                                const ushort* __restrict__ Bt,
                                                ushort* __restrict__ C,
                                                const float* __restrict__ att_s,
                                                const float* __restrict__ att_d,
                                                float* __restrict__ a_s,
                                                float* __restrict__ a_d,
                                                int M, int N, int K, int H) {
  __shared__ ushort As[128][72];
  __shared__ ushort Bs[64][72];
  int tid = threadIdx.x;
  int w = tid >> 6, l = tid & 63;
  int bm = blockIdx.y * 128, bn = blockIdx.x * 64;
  int fr = l & 15, fg = l >> 4, fk = fg * 8;
  f32x4 acc[2][4];
#pragma unroll
  for (int ar = 0; ar < 2; ++ar)
#pragma unroll
    for (int nb = 0; nb < 4; ++nb) acc[ar][nb] = (f32x4){0.f, 0.f, 0.f, 0.f};
  for (int k0 = 0; k0 < K; k0 += 64) {
#pragma unroll
    for (int i = 0; i < 4; ++i) {
      int s = tid + i * 256;
      int row = s >> 3, sc = (s & 7) * 8;
      bf16x8 v = {0, 0, 0, 0, 0, 0, 0, 0};
      if (bm + row < M) v = *(const bf16x8*)(A + (size_t)(bm + row) * K + k0 + sc);
      *(bf16x8*)&As[row][sc] = v;
    }
#pragma unroll
    for (int i = 0; i < 2; ++i) {
      int s = tid + i * 256;
      int row = s >> 3, sc = (s & 7) * 8;
      bf16x8 v = *(const bf16x8*)(Bt + (size_t)(bn + row) * K + k0 + sc);
      *(bf16x8*)&Bs[row][sc] = v;
    }
    __syncthreads();
#pragma unroll
    for (int kk = 0; kk < 64; kk += 32) {
      bf16x8 a0 = *(bf16x8*)&As[32 * w + fr][kk + fk];
      bf16x8 a1 = *(bf16x8*)&As[32 * w + 16 + fr][kk + fk];
#pragma unroll
      for (int nb = 0; nb < 4; ++nb) {
        bf16x8 b = *(bf16x8*)&Bs[nb * 16 + fr][kk + fk];
        acc[0][nb] = __builtin_amdgcn_mfma_f32_16x16x32_bf16(a0, b, acc[0][nb], 0, 0, 0);
        acc[1][nb] = __builtin_amdgcn_mfma_f32_16x16x32_bf16(a1, b, acc[1][nb], 0, 0, 0);
      }
    }
    __syncthreads();
  }
  int h = bn >> 6;
  float asc[4], adc[4];
#pragma unroll
  for (int nb = 0; nb < 4; ++nb) {
    asc[nb] = att_s[h * 64 + nb * 16 + fr];
    adc[nb] = att_d[h * 64 + nb * 16 + fr];
  }
#pragma unroll
  for (int ar = 0; ar < 2; ++ar) {
#pragma unroll
    for (int r = 0; r < 4; ++r) {
      float vs = 0.f, vd = 0.f;
#pragma unroll
      for (int nb = 0; nb < 4; ++nb) {
        vs = fmaf(acc[ar][nb][r], asc[nb], vs);
        vd = fmaf(acc[ar][nb][r], adc[nb], vd);
      }
#pragma unroll
      for (int off = 1; off < 16; off <<= 1) {
        vs += __shfl_xor(vs, off);
        vd += __shfl_xor(vd, off);
      }
      int row = bm + 32 * w + 16 * ar + fg * 4 + r;
      if (fr == 0 && row < M) {
        a_s[(size_t)row * H + h] = vs;
        a_d[(size_t)row * H + h] = vd;
      }
    }
#pragma unroll
    for (int nb = 0; nb < 4; ++nb)
#pragma unroll
      for (int r = 0; r < 4; ++r) {
        int row = bm + 32 * w + 16 * ar + fg * 4 + r;
        if (row < M) C[(size_t)row * N + bn + nb * 16 + fr] = f2bf(acc[ar][nb][r]);
      }
  }
}

// ---------------- fused softmax + aggregation, H=4 ----------------
// wave = node; lane = (head l>>4, 4 channels). Fast path deg<=64: e/sidx cached
// in registers, one wave-max + wave-sum per head. Slow path (deg>64): 2 passes.

template <int WPB, int ACT>
__global__ __launch_bounds__(64 * WPB) void fagg4_k(
    const ushort* __restrict__ xw, const float4* __restrict__ a_s4,
    const float4* __restrict__ a_d4, const int* __restrict__ rowptr,
    const int* __restrict__ csr_src, const float* __restrict__ bias,
    ushort* __restrict__ hout, int N) {
  __shared__ float pbuf[WPB][4][66];
  int w = threadIdx.x >> 6, l = threadIdx.x & 63;
  int n = blockIdx.x * WPB + w;
  if (n >= N) return;
  int h = l >> 4;
  int beg = rowptr[n], end = rowptr[n + 1];
  int deg = end - beg;
  float4 ad = a_d4[n];
  f32x4 a0 = {0.f, 0.f, 0.f, 0.f}, a1 = {0.f, 0.f, 0.f, 0.f};
  f32x4 a2 = {0.f, 0.f, 0.f, 0.f}, a3 = {0.f, 0.f, 0.f, 0.f};
  const ushort4* xw4 = (const ushort4*)xw;
  float s0, s1, s2, s3;

  if (deg <= 64) {
    // ---- fast path: single chunk ----
    int cnt = deg;
    float e0 = -1e30f, e1 = -1e30f, e2 = -1e30f, e3 = -1e30f;
    int sidx = 0;
    if (l < cnt) {
      sidx = csr_src[beg + l];
      float4 as = a_s4[sidx];
      e0 = lrelu(as.x + ad.x); e1 = lrelu(as.y + ad.y);
      e2 = lrelu(as.z + ad.z); e3 = lrelu(as.w + ad.w);
    }
    float m0 = wave_max64(e0), m1 = wave_max64(e1);
    float m2 = wave_max64(e2), m3 = wave_max64(e3);
    float p0 = __expf(e0 - m0), p1 = __expf(e1 - m1);
    float p2 = __expf(e2 - m2), p3 = __expf(e3 - m3);
    s0 = wave_sum64(p0); s1 = wave_sum64(p1);
    s2 = wave_sum64(p2); s3 = wave_sum64(p3);
    pbuf[w][0][l] = p0; pbuf[w][1][l] = p1;
    pbuf[w][2][l] = p2; pbuf[w][3][l] = p3;
    // single-wave LDS producer/consumer: in-order, no barrier
    int j = 0;
    for (; j + 4 <= cnt; j += 4) {
      int t0 = __builtin_amdgcn_readlane(sidx, j);
      int t1 = __builtin_amdgcn_readlane(sidx, j + 1);
      int t2 = __builtin_amdgcn_readlane(sidx, j + 2);
      int t3 = __builtin_amdgcn_readlane(sidx, j + 3);
      float q0 = pbuf[w][h][j], q1 = pbuf[w][h][j + 1];
      float q2 = pbuf[w][h][j + 2], q3 = pbuf[w][h][j + 3];
      ushort4 v0 = xw4[(size_t)t0 * 64 + l];
      ushort4 v1 = xw4[(size_t)t1 * 64 + l];
      ushort4 v2 = xw4[(size_t)t2 * 64 + l];
      ushort4 v3 = xw4[(size_t)t3 * 64 + l];
      a0[0] = fmaf(q0, bf2f(v0.x), a0[0]); a0[1] = fmaf(q0, bf2f(v0.y), a0[1]);
      a0[2] = fmaf(q0, bf2f(v0.z), a0[2]); a0[3] = fmaf(q0, bf2f(v0.w), a0[3]);
      a1[0] = fmaf(q1, bf2f(v1.x), a1[0]); a1[1] = fmaf(q1, bf2f(v1.y), a1[1]);
      a1[2] = fmaf(q1, bf2f(v1.z), a1[2]); a1[3] = fmaf(q1, bf2f(v1.w), a1[3]);
      a2[0] = fmaf(q2, bf2f(v2.x), a2[0]); a2[1] = fmaf(q2, bf2f(v2.y), a2[1]);
      a2[2] = fmaf(q2, bf2f(v2.z), a2[2]); a2[3] = fmaf(q2, bf2f(v2.w), a2[3]);
      a3[0] = fmaf(q3, bf2f(v3.x), a3[0]); a3[1] = fmaf(q3, bf2f(v3.y), a3[1]);
      a3[2] = fmaf(q3, bf2f(v3.z), a3[2]); a3[3] = fmaf(q3, bf2f(v3.w), a3[3]);
    }
    for (; j < cnt; ++j) {
      int tj = __builtin_amdgcn_readlane(sidx, j);
      float qj = pbuf[w][h][j];
      ushort4 v = xw4[(size_t)tj * 64 + l];
      a0[0] = fmaf(qj, bf2f(v.x), a0[0]); a0[1] = fmaf(qj, bf2f(v.y), a0[1]);
      a0[2] = fmaf(qj, bf2f(v.z), a0[2]); a0[3] = fmaf(qj, bf2f(v.w), a0[3]);
    }
  } else {
    // ---- slow path (deg > 64, ~never for this graph): two passes ----
    float m0 = -1e30f, m1 = -1e30f, m2 = -1e30f, m3 = -1e30f;
    for (int c0 = beg; c0 < end; c0 += 64) {
      int cnt = min(64, end - c0);
      float e0 = -1e30f, e1 = -1e30f, e2 = -1e30f, e3 = -1e30f;
      if (l < cnt) {
        float4 as = a_s4[csr_src[c0 + l]];
        e0 = lrelu(as.x + ad.x); e1 = lrelu(as.y + ad.y);
        e2 = lrelu(as.z + ad.z); e3 = lrelu(as.w + ad.w);
      }
      m0 = fmaxf(m0, wave_max64(e0)); m1 = fmaxf(m1, wave_max64(e1));
      m2 = fmaxf(m2, wave_max64(e2)); m3 = fmaxf(m3, wave_max64(e3));
    }
    s0 = s1 = s2 = s3 = 0.f;
    for (int c0 = beg; c0 < end; c0 += 64) {
      int cnt = min(64, end - c0);
      int sidx = 0;
      float p0 = 0.f, p1 = 0.f, p2 = 0.f, p3 = 0.f;
      if (l < cnt) {
        sidx = csr_src[c0 + l];
        float4 as = a_s4[sidx];
        p0 = __expf(lrelu(as.x + ad.x) - m0);
        p1 = __expf(lrelu(as.y + ad.y) - m1);
        p2 = __expf(lrelu(as.z + ad.z) - m2);
        p3 = __expf(lrelu(as.w + ad.w) - m3);
      }
      s0 += wave_sum64(p0); s1 += wave_sum64(p1);
      s2 += wave_sum64(p2); s3 += wave_sum64(p3);
      pbuf[w][0][l] = p0; pbuf[w][1][l] = p1;
      pbuf[w][2][l] = p2; pbuf[w][3][l] = p3;
      for (int j = 0; j < cnt; ++j) {
        int tj = __builtin_amdgcn_readlane(sidx, j);
        float qj = pbuf[w][h][j];
        ushort4 v = xw4[(size_t)tj * 64 + l];
        a0[0] = fmaf(qj, bf2f(v.x), a0[0]); a0[1] = fmaf(qj, bf2f(v.y), a0[1]);
        a0[2] = fmaf(qj, bf2f(v.z), a0[2]); a0[3] = fmaf(qj, bf2f(v.w), a0[3]);
      }
    }
  }

  float smy = h == 0 ? s0 : h == 1 ? s1 : h == 2 ? s2 : s3;
  float inv = 1.f / smy;
  float4 bv = ((const float4*)bias)[l];
  float o0 = ((a0[0] + a1[0]) + (a2[0] + a3[0])) * inv + bv.x;
  float o1 = ((a0[1] + a1[1]) + (a2[1] + a3[1])) * inv + bv.y;
  float o2 = ((a0[2] + a1[2]) + (a2[2] + a3[2])) * inv + bv.z;
  float o3 = ((a0[3] + a1[3]) + (a2[3] + a3[3])) * inv + bv.w;
  if (ACT) {
    o0 = o0 > 0.f ? o0 : __expf(o0) - 1.f;
    o1 = o1 > 0.f ? o1 : __expf(o1) - 1.f;
    o2 = o2 > 0.f ? o2 : __expf(o2) - 1.f;
    o3 = o3 > 0.f ? o3 : __expf(o3) - 1.f;
  }
  ushort4 ov;
  ov.x = f2bf(o0); ov.y = f2bf(o1); ov.z = f2bf(o2); ov.w = f2bf(o3);
  ((ushort4*)(hout + (size_t)n * 256))[l] = ov;
}

// ---------------- fused softmax + aggregation, H=1 (layer 3) ----------------
// softmax: lane = edge; gather: 16-lane groups (g=l>>4) x 4 edges/iter.

template <int WPB>
__global__ __launch_bounds__(64 * WPB) void fagg1_k(
    const ushort* __restrict__ xw, const float* __restrict__ a_s,
    const float* __restrict__ a_d, const int* __restrict__ rowptr,
    const int* __restrict__ csr_src, const float* __restrict__ bias,
    float* __restrict__ hout, int N) {
  __shared__ float pbuf[WPB][64];
  __shared__ int sbuf[WPB][64];
  int w = threadIdx.x >> 6, l = threadIdx.x & 63;
  int n = blockIdx.x * WPB + w;
  if (n >= N) return;
  int g = l >> 4, q = l & 15;
  int beg = rowptr[n], end = rowptr[n + 1];
  int deg = end - beg;
  float ad = a_d[n];
  f32x4 acc = {0.f, 0.f, 0.f, 0.f};
  const ushort4* xw4 = (const ushort4*)xw;
  float ss;

  if (deg <= 64) {
    int cnt = deg;
    float e = -1e30f;
    int sidx = 0;
    if (l < cnt) {
      sidx = csr_src[beg + l];
      e = lrelu(a_s[sidx] + ad);
    }
    float m = wave_max64(e);
    float p = __expf(e - m);
    ss = wave_sum64(p);
    pbuf[w][l] = p;
    sbuf[w][l] = sidx;
    for (int j = 0; j < cnt; j += 4) {
      int jj = j + g;
      bool ok = jj < cnt;
      int idx = ok ? jj : 0;
      float pj = ok ? pbuf[w][idx] : 0.f;
      int sj = sbuf[w][idx];
      ushort4 v = xw4[(size_t)sj * 16 + q];
      acc[0] = fmaf(pj, bf2f(v.x), acc[0]);
      acc[1] = fmaf(pj, bf2f(v.y), acc[1]);
      acc[2] = fmaf(pj, bf2f(v.z), acc[2]);
      acc[3] = fmaf(pj, bf2f(v.w), acc[3]);
    }
  } else {
    float m = -1e30f;
    for (int c0 = beg; c0 < end; c0 += 64) {
      int cnt = min(64, end - c0);
      float e = -1e30f;
      if (l < cnt) e = lrelu(a_s[csr_src[c0 + l]] + ad);
      m = fmaxf(m, wave_max64(e));
    }
    ss = 0.f;
    for (int c0 = beg; c0 < end; c0 += 64) {
      int cnt = min(64, end - c0);
      int sidx = 0;
      float p = 0.f;
      if (l < cnt) {
        sidx = csr_src[c0 + l];
        p = __expf(lrelu(a_s[sidx] + ad) - m);
      }
      ss += wave_sum64(p);
      pbuf[w][l] = p;
      sbuf[w][l] = sidx;
      for (int j = 0; j < cnt; j += 4) {
        int jj = j + g;
        bool ok = jj < cnt;
        int idx = ok ? jj : 0;
        float pj = ok ? pbuf[w][idx] : 0.f;
        int sj = sbuf[w][idx];
        ushort4 v = xw4[(size_t)sj * 16 + q];
        acc[0] = fmaf(pj, bf2f(v.x), acc[0]);
        acc[1] = fmaf(pj, bf2f(v.y), acc[1]);
        acc[2] = fmaf(pj, bf2f(v.z), acc[2]);
        acc[3] = fmaf(pj, bf2f(v.w), acc[3]);
      }
    }
  }
#pragma unroll
  for (int i = 0; i < 4; ++i) {
    acc[i] += __shfl_xor(acc[i], 16);
    acc[i] += __shfl_xor(acc[i], 32);
  }
  float inv = 1.f / ss;
  float4 bv = ((const float4*)bias)[q];
  float4 o;
  o.x = acc[0] * inv + bv.x;
  o.y = acc[1] * inv + bv.y;
  o.z = acc[2] * inv + bv.z;
  o.w = acc[3] * inv + bv.w;
  if (g == 0) ((float4*)(hout + (size_t)n * 64))[q] = o;
}

// ---------------- final mean over nodes + classifier ----------------

__global__ void reduce_mean_k(const float* __restrict__ h3, float* __restrict__ g, int N) {
  __shared__ float sm[4][64];
  int w = threadIdx.x >> 6;
  int lane = threadIdx.x & 63;
  float acc = 0.f;
  for (int n = blockIdx.x * 4 + w; n < N; n += gridDim.x * 4)
    acc += h3[(size_t)n * 64 + lane];
  sm[w][lane] = acc;
  __syncthreads();
  if (w == 0) {
    float t = sm[0][lane] + sm[1][lane] + sm[2][lane] + sm[3][lane];
    atomicAdd(&g[lane], t);
  }
}

__global__ void final_k(const float* __restrict__ g, const float* __restrict__ Wc,
                        const float* __restrict__ bc, float* __restrict__ out, int N) {
  int lane = threadIdx.x;  // 64
  float gc = g[lane] / (float)N;
  for (int j = 0; j < 10; ++j) {
    float v = gc * Wc[lane * 10 + j];
    for (int off = 32; off; off >>= 1) v += __shfl_down(v, off);
    if (lane == 0) out[j] = v + bc[j];
  }
}

// ---------------- launch ----------------

extern "C" void kernel_launch(void* const* d_in, const int* in_sizes, int n_in,
                              void* d_out, int out_size, void* d_ws, size_t ws_size,
                              hipStream_t stream) {
  const float* x   = (const float*)d_in[0];
  const int*   ei  = (const int*)d_in[1];
  const float* W1  = (const float*)d_in[2];
  const float* as1 = (const float*)d_in[3];
  const float* ad1 = (const float*)d_in[4];
  const float* b1  = (const float*)d_in[5];
  const float* W2  = (const float*)d_in[6];
  const float* as2 = (const float*)d_in[7];
  const float* ad2 = (const float*)d_in[8];
  const float* b2  = (const float*)d_in[9];
  const float* W3  = (const float*)d_in[10];
  const float* as3 = (const float*)d_in[11];
  const float* ad3 = (const float*)d_in[12];
  const float* b3  = (const float*)d_in[13];
  const float* Wc  = (const float*)d_in[14];
  const float* bc  = (const float*)d_in[15];
  float* out = (float*)d_out;

  int N = in_sizes[0] / 128;
  int E = in_sizes[1] / 2;
  int E2 = E + N;

  char* w = (char*)d_ws;
  auto alloc = [&](size_t bytes) {
    char* p = w;
    w += (bytes + 255) & ~(size_t)255;
    return p;
  };
  ushort* xb   = (ushort*)alloc((size_t)N * 128 * 2);  // reused as h3f (layer 3, f32[N][64])
  float*  h3f  = (float*)xb;
  ushort* xwb  = (ushort*)alloc((size_t)N * 256 * 2);
  ushort* hb   = (ushort*)alloc((size_t)N * 256 * 2);
  ushort* w1t  = (ushort*)alloc((size_t)256 * 128 * 2);
  ushort* w2t  = (ushort*)alloc((size_t)256 * 256 * 2);
  ushort* w3t  = (ushort*)alloc((size_t)64 * 256 * 2);
  float*  a_s  = (float*)alloc((size_t)N * 4 * 4);
  float*  a_d  = (float*)alloc((size_t)N * 4 * 4);
  int*   deg    = (int*)alloc((size_t)N * 4);
  int*   excl   = (int*)alloc((size_t)N * 4);
  int*   bsum   = (int*)alloc(64 * 4);
  int*   rowptr = (int*)alloc((size_t)(N + 1) * 4);
  int*   eoff   = (int*)alloc((size_t)E2 * 4);
  int*   csr    = (int*)alloc((size_t)E2 * 4);
  float* g      = (float*)alloc(64 * 4);

  hipMemsetAsync(deg, 0, (size_t)N * 4, stream);
  hipMemsetAsync(g, 0, 64 * 4, stream);

  // conversions
  f2b_k<<<(N * 128 / 4 + 255) / 256, 256, 0, stream>>>(x, xb, N * 128 / 4);
  wtrans3_k<<<dim3(16, 16, 3), 256, 0, stream>>>(W1, W2, W3, w1t, w2t, w3t);

  // CSR
  int gE2 = (E2 + 255) / 256;
  histoff_k<<<gE2, 256, 0, stream>>>(ei, E, E2, deg, eoff);
  int nb = (N + 1023) / 1024;
  scan1_k<<<nb, 256, 0, stream>>>(deg, excl, bsum, N);
  scan2_k<<<1, 64, 0, stream>>>(bsum, nb);
  scan3_k<<<(N + 256) / 256, 256, 0, stream>>>(excl, bsum, rowptr, N, E2);
  scatter_k<<<gE2, 256, 0, stream>>>(ei, E, E2, rowptr, eoff, csr);

  int mb = (N + 127) / 128;
  int nwb = (N + 3) / 4;
  // layer 1
  gemm_att<<<dim3(4, mb), 256, 0, stream>>>(xb, w1t, xwb, as1, ad1, a_s, a_d, N, 256, 128, 4);
  fagg4_k<4, 1><<<nwb, 256, 0, stream>>>(xwb, (const float4*)a_s, (const float4*)a_d,
                                         rowptr, csr, b1, hb, N);
  // layer 2
  gemm_att<<<dim3(4, mb), 256, 0, stream>>>(hb, w2t, xwb, as2, ad2, a_s, a_d, N, 256, 256, 4);
  fagg4_k<4, 1><<<nwb, 256, 0, stream>>>(xwb, (const float4*)a_s, (const float4*)a_d,
                                         rowptr, csr, b2, hb, N);
  // layer 3 (single head)
  gemm_att<<<dim3(1, mb), 256, 0, stream>>>(hb, w3t, xwb, as3, ad3, a_s, a_d, N, 64, 256, 1);
  fagg1_k<4><<<nwb, 256, 0, stream>>>(xwb, a_s, a_d, rowptr, csr, b3, h3f, N);

  reduce_mean_k<<<256, 256, 0, stream>>>(h3f, g, N);
  final_k<<<1, 64, 0, stream>>>(g, Wc, bc, out, N);
}

// Round 9
// 369.356 us; speedup vs baseline: 1.3714x; 1.1248x over previous
//
#include <hip/hip_runtime.h>

#define NEG_SLOPE 0.2f

typedef __attribute__((ext_vector_type(8))) short bf16x8;
typedef __attribute__((ext_vector_type(4))) float f32x4;

__device__ __forceinline__ float bf2f(ushort u) {
  return __uint_as_float(((unsigned int)u) << 16);
}
__device__ __forceinline__ ushort f2bf(float f) {  // round-to-nearest-even
  unsigned int u = __float_as_uint(f);
  u += 0x7fff + ((u >> 16) & 1);
  return (ushort)(u >> 16);
}
__device__ __forceinline__ float lrelu(float e) { return e > 0.f ? e : NEG_SLOPE * e; }

// ---- OCP e4m3 helpers (HW cvt on gfx950; bit-twiddled fallback kept consistent) ----
#if defined(__has_builtin)
#if __has_builtin(__builtin_amdgcn_cvt_f32_fp8) && __has_builtin(__builtin_amdgcn_cvt_pk_fp8_f32)
#define HW_FP8 1
#endif
#endif

__device__ __forceinline__ unsigned char ftofp8(float f) {
#ifdef HW_FP8
  unsigned int pk = __builtin_amdgcn_cvt_pk_fp8_f32(f, f, 0, false);
  return (unsigned char)(pk & 0xff);
#else
  float c = fminf(fmaxf(f, -448.f), 448.f);
  float y = c * 0x1.0p-120f;
  unsigned int u = __float_as_uint(y);
  unsigned int lsb = (u >> 20) & 1u;
  u += 0x7ffffu + lsb;
  return (unsigned char)(((u >> 24) & 0x80u) | ((u >> 20) & 0x7fu));
#endif
}

#ifdef HW_FP8
#define FP8DEC(u, s) __builtin_amdgcn_cvt_f32_fp8((u), (s))
#else
__device__ __forceinline__ float fp8dec_sw(unsigned int u, int sel) {
  unsigned int b = (u >> (8 * sel)) & 0xffu;
  unsigned int f = ((b & 0x80u) << 24) | ((b & 0x7fu) << 20);
  return __uint_as_float(f) * 0x1.0p+120f;
}
#define FP8DEC(u, s) fp8dec_sw((u), (s))
#endif

__device__ __forceinline__ float wave_max64(float v) {
  for (int off = 32; off; off >>= 1) v = fmaxf(v, __shfl_xor(v, off));
  return v;
}
__device__ __forceinline__ float wave_sum64(float v) {
  for (int off = 32; off; off >>= 1) v += __shfl_xor(v, off);
  return v;
}

// ---------------- CSR build ----------------

__global__ void histoff_k(const int* __restrict__ ei, int E, int E2,
                          int* __restrict__ deg, int* __restrict__ eoff) {
  int i = blockIdx.x * 256 + threadIdx.x;
  if (i >= E2) return;
  int d = (i < E) ? ei[E + i] : (i - E);
  eoff[i] = atomicAdd(&deg[d], 1);
}

__global__ void scan1_k(const int* __restrict__ deg, int* __restrict__ excl,
                        int* __restrict__ bsum, int N) {
  __shared__ int sm[256];
  int t = threadIdx.x;
  int base = blockIdx.x * 1024 + t * 4;
  int v0 = (base + 0 < N) ? deg[base + 0] : 0;
  int v1 = (base + 1 < N) ? deg[base + 1] : 0;
  int v2 = (base + 2 < N) ? deg[base + 2] : 0;
  int v3 = (base + 3 < N) ? deg[base + 3] : 0;
  int tsum = v0 + v1 + v2 + v3;
  sm[t] = tsum;
  __syncthreads();
  for (int off = 1; off < 256; off <<= 1) {
    int x = (t >= off) ? sm[t - off] : 0;
    __syncthreads();
    sm[t] += x;
    __syncthreads();
  }
  int run = sm[t] - tsum;
  if (base + 0 < N) excl[base + 0] = run; run += v0;
  if (base + 1 < N) excl[base + 1] = run; run += v1;
  if (base + 2 < N) excl[base + 2] = run; run += v2;
  if (base + 3 < N) excl[base + 3] = run;
  if (t == 255) bsum[blockIdx.x] = sm[255];
}

__global__ void scan2_k(int* __restrict__ bsum, int nb) {
  int t = threadIdx.x;
  int orig = (t < nb) ? bsum[t] : 0;
  int v = orig;
  for (int off = 1; off < 64; off <<= 1) {
    int x = __shfl_up(v, off);
    if (t >= off) v += x;
  }
  if (t < nb) bsum[t] = v - orig;
}

__global__ void scan3_k(const int* __restrict__ excl, const int* __restrict__ bsum,
                        int* __restrict__ rowptr, int N, int E2) {
  int i = blockIdx.x * 256 + threadIdx.x;
  if (i < N) rowptr[i] = excl[i] + bsum[i >> 10];
  if (i == N) rowptr[N] = E2;
}

__global__ void scatter_k(const int* __restrict__ ei, int E, int E2,
                          const int* __restrict__ rowptr, const int* __restrict__ eoff,
                          int* __restrict__ csr_src) {
  int i = blockIdx.x * 256 + threadIdx.x;
  if (i >= E2) return;
  int s, d;
  if (i < E) { s = ei[i]; d = ei[E + i]; }
  else       { s = d = i - E; }
  csr_src[rowptr[d] + eoff[i]] = s;
}

// ---------------- conversions ----------------

__global__ void f2b_k(const float* __restrict__ in, ushort* __restrict__ out, int n4) {
  int i = blockIdx.x * 256 + threadIdx.x;
  if (i >= n4) return;
  float4 v = ((const float4*)in)[i];
  ushort4 o;
  o.x = f2bf(v.x); o.y = f2bf(v.y); o.z = f2bf(v.z); o.w = f2bf(v.w);
  ((ushort4*)out)[i] = o;
}

__global__ void wtrans3_k(const float* __restrict__ W1, const float* __restrict__ W2,
                          const float* __restrict__ W3, ushort* __restrict__ w1t,
                          ushort* __restrict__ w2t, ushort* __restrict__ w3t) {
  int z = blockIdx.z;
  const float* W = z == 0 ? W1 : z == 1 ? W2 : W3;
  ushort* Wt = z == 0 ? w1t : z == 1 ? w2t : w3t;
  int K = z == 0 ? 128 : 256;
  int Nc = z == 2 ? 64 : 256;
  int k = blockIdx.x * 16 + (threadIdx.x & 15);
  int n = blockIdx.y * 16 + (threadIdx.x >> 4);
  if (k < K && n < Nc) Wt[(size_t)n * K + k] = f2bf(W[(size_t)k * Nc + n]);
}

// ------- bf16 MFMA GEMM + fused attention coefficients; C written as fp8 -------

__global__ __launch_bounds__(256) void gemm_att(const ushort* __restrict__ A,
                                                const ushort* __restrict__ Bt,
                                                unsigned char* __restrict__ C,
                                                const float* __restrict__ att_s,
                                                const float* __restrict__ att_d,
                                                float* __restrict__ a_s,
                                                float* __restrict__ a_d,
                                                int M, int N, int K, int H) {
  __shared__ ushort As[128][72];
  __shared__ ushort Bs[64][72];
  int tid = threadIdx.x;
  int w = tid >> 6, l = tid & 63;
  int bm = blockIdx.y * 128, bn = blockIdx.x * 64;
  int fr = l & 15, fg = l >> 4, fk = fg * 8;
  f32x4 acc[2][4];
#pragma unroll
  for (int ar = 0; ar < 2; ++ar)
#pragma unroll
    for (int nb = 0; nb < 4; ++nb) acc[ar][nb] = (f32x4){0.f, 0.f, 0.f, 0.f};
  for (int k0 = 0; k0 < K; k0 += 64) {
#pragma unroll
    for (int i = 0; i < 4; ++i) {
      int s = tid + i * 256;
      int row = s >> 3, sc = (s & 7) * 8;
      bf16x8 v = {0, 0, 0, 0, 0, 0, 0, 0};
      if (bm + row < M) v = *(const bf16x8*)(A + (size_t)(bm + row) * K + k0 + sc);
      *(bf16x8*)&As[row][sc] = v;
    }
#pragma unroll
    for (int i = 0; i < 2; ++i) {
      int s = tid + i * 256;
      int row = s >> 3, sc = (s & 7) * 8;
      bf16x8 v = *(const bf16x8*)(Bt + (size_t)(bn + row) * K + k0 + sc);
      *(bf16x8*)&Bs[row][sc] = v;
    }
    __syncthreads();
#pragma unroll
    for (int kk = 0; kk < 64; kk += 32) {
      bf16x8 a0 = *(bf16x8*)&As[32 * w + fr][kk + fk];
      bf16x8 a1 = *(bf16x8*)&As[32 * w + 16 + fr][kk + fk];
#pragma unroll
      for (int nb = 0; nb < 4; ++nb) {
        bf16x8 b = *(bf16x8*)&Bs[nb * 16 + fr][kk + fk];
        acc[0][nb] = __builtin_amdgcn_mfma_f32_16x16x32_bf16(a0, b, acc[0][nb], 0, 0, 0);
        acc[1][nb] = __builtin_amdgcn_mfma_f32_16x16x32_bf16(a1, b, acc[1][nb], 0, 0, 0);
      }
    }
    __syncthreads();
  }
  int h = bn >> 6;
  float asc[4], adc[4];
#pragma unroll
  for (int nb = 0; nb < 4; ++nb) {
    asc[nb] = att_s[h * 64 + nb * 16 + fr];
    adc[nb] = att_d[h * 64 + nb * 16 + fr];
  }
#pragma unroll
  for (int ar = 0; ar < 2; ++ar) {
#pragma unroll
    for (int r = 0; r < 4; ++r) {
      float vs = 0.f, vd = 0.f;
#pragma unroll
      for (int nb = 0; nb < 4; ++nb) {
        vs = fmaf(acc[ar][nb][r], asc[nb], vs);
        vd = fmaf(acc[ar][nb][r], adc[nb], vd);
      }
#pragma unroll
      for (int off = 1; off < 16; off <<= 1) {
        vs += __shfl_xor(vs, off);
        vd += __shfl_xor(vd, off);
      }
      int row = bm + 32 * w + 16 * ar + fg * 4 + r;
      if (fr == 0 && row < M) {
        a_s[(size_t)row * H + h] = vs;
        a_d[(size_t)row * H + h] = vd;
      }
    }
#pragma unroll
    for (int nb = 0; nb < 4; ++nb)
#pragma unroll
      for (int r = 0; r < 4; ++r) {
        int row = bm + 32 * w + 16 * ar + fg * 4 + r;
        if (row < M) C[(size_t)row * N + bn + nb * 16 + fr] = ftofp8(acc[ar][nb][r]);
      }
  }
}

// ---------------- fused softmax + aggregation, H=4 (fp8 gather table) ----------------
// wave = node; lane = (head l>>4, 4 channels). Row = 256 fp8 = 256B; uint/lane.

template <int WPB, int ACT>
__global__ __launch_bounds__(64 * WPB) void fagg4_k(
    const unsigned char* __restrict__ xw, const float4* __restrict__ a_s4,
    const float4* __restrict__ a_d4, const int* __restrict__ rowptr,
    const int* __restrict__ csr_src, const float* __restrict__ bias,
    ushort* __restrict__ hout, int N) {
  __shared__ float pbuf[WPB][4][66];
  int w = threadIdx.x >> 6, l = threadIdx.x & 63;
  int n = blockIdx.x * WPB + w;
  if (n >= N) return;
  int h = l >> 4;
  int beg = rowptr[n], end = rowptr[n + 1];
  int deg = end - beg;
  float4 ad = a_d4[n];
  f32x4 a0 = {0.f, 0.f, 0.f, 0.f}, a1 = {0.f, 0.f, 0.f, 0.f};
  f32x4 a2 = {0.f, 0.f, 0.f, 0.f}, a3 = {0.f, 0.f, 0.f, 0.f};
  const unsigned int* xwu = (const unsigned int*)xw;
  float s0, s1, s2, s3;

  if (deg <= 64) {
    int cnt = deg;
    float e0 = -1e30f, e1 = -1e30f, e2 = -1e30f, e3 = -1e30f;
    int sidx = 0;
    if (l < cnt) {
      sidx = csr_src[beg + l];
      float4 as = a_s4[sidx];
      e0 = lrelu(as.x + ad.x); e1 = lrelu(as.y + ad.y);
      e2 = lrelu(as.z + ad.z); e3 = lrelu(as.w + ad.w);
    }
    float m0 = wave_max64(e0), m1 = wave_max64(e1);
    float m2 = wave_max64(e2), m3 = wave_max64(e3);
    float p0 = __expf(e0 - m0), p1 = __expf(e1 - m1);
    float p2 = __expf(e2 - m2), p3 = __expf(e3 - m3);
    s0 = wave_sum64(p0); s1 = wave_sum64(p1);
    s2 = wave_sum64(p2); s3 = wave_sum64(p3);
    pbuf[w][0][l] = p0; pbuf[w][1][l] = p1;
    pbuf[w][2][l] = p2; pbuf[w][3][l] = p3;
    // single-wave LDS producer/consumer: in-order, no barrier
    int j = 0;
    for (; j + 4 <= cnt; j += 4) {
      int t0 = __builtin_amdgcn_readlane(sidx, j);
      int t1 = __builtin_amdgcn_readlane(sidx, j + 1);
      int t2 = __builtin_amdgcn_readlane(sidx, j + 2);
      int t3 = __builtin_amdgcn_readlane(sidx, j + 3);
      float q0 = pbuf[w][h][j], q1 = pbuf[w][h][j + 1];
      float q2 = pbuf[w][h][j + 2], q3 = pbuf[w][h][j + 3];
      unsigned int u0 = xwu[(size_t)t0 * 64 + l];
      unsigned int u1 = xwu[(size_t)t1 * 64 + l];
      unsigned int u2 = xwu[(size_t)t2 * 64 + l];
      unsigned int u3 = xwu[(size_t)t3 * 64 + l];
      a0[0] = fmaf(q0, FP8DEC(u0, 0), a0[0]); a0[1] = fmaf(q0, FP8DEC(u0, 1), a0[1]);
      a0[2] = fmaf(q0, FP8DEC(u0, 2), a0[2]); a0[3] = fmaf(q0, FP8DEC(u0, 3), a0[3]);
      a1[0] = fmaf(q1, FP8DEC(u1, 0), a1[0]); a1[1] = fmaf(q1, FP8DEC(u1, 1), a1[1]);
      a1[2] = fmaf(q1, FP8DEC(u1, 2), a1[2]); a1[3] = fmaf(q1, FP8DEC(u1, 3), a1[3]);
      a2[0] = fmaf(q2, FP8DEC(u2, 0), a2[0]); a2[1] = fmaf(q2, FP8DEC(u2, 1), a2[1]);
      a2[2] = fmaf(q2, FP8DEC(u2, 2), a2[2]); a2[3] = fmaf(q2, FP8DEC(u2, 3), a2[3]);
      a3[0] = fmaf(q3, FP8DEC(u3, 0), a3[0]); a3[1] = fmaf(q3, FP8DEC(u3, 1), a3[1]);
      a3[2] = fmaf(q3, FP8DEC(u3, 2), a3[2]); a3[3] = fmaf(q3, FP8DEC(u3, 3), a3[3]);
    }
    for (; j < cnt; ++j) {
      int tj = __builtin_amdgcn_readlane(sidx, j);
      float qj = pbuf[w][h][j];
      unsigned int u = xwu[(size_t)tj * 64 + l];
      a0[0] = fmaf(qj, FP8DEC(u, 0), a0[0]); a0[1] = fmaf(qj, FP8DEC(u, 1), a0[1]);
      a0[2] = fmaf(qj, FP8DEC(u, 2), a0[2]); a0[3] = fmaf(qj, FP8DEC(u, 3), a0[3]);
    }
  } else {
    // slow path (deg > 64): two passes
    float m0 = -1e30f, m1 = -1e30f, m2 = -1e30f, m3 = -1e30f;
    for (int c0 = beg; c0 < end; c0 += 64) {
      int cnt = min(64, end - c0);
      float e0 = -1e30f, e1 = -1e30f, e2 = -1e30f, e3 = -1e30f;
      if (l < cnt) {
        float4 as = a_s4[csr_src[c0 + l]];
        e0 = lrelu(as.x + ad.x); e1 = lrelu(as.y + ad.y);
        e2 = lrelu(as.z + ad.z); e3 = lrelu(as.w + ad.w);
      }
      m0 = fmaxf(m0, wave_max64(e0)); m1 = fmaxf(m1, wave_max64(e1));
      m2 = fmaxf(m2, wave_max64(e2)); m3 = fmaxf(m3, wave_max64(e3));
    }
    s0 = s1 = s2 = s3 = 0.f;
    for (int c0 = beg; c0 < end; c0 += 64) {
      int cnt = min(64, end - c0);
      int sidx = 0;
      float p0 = 0.f, p1 = 0.f, p2 = 0.f, p3 = 0.f;
      if (l < cnt) {
        sidx = csr_src[c0 + l];
        float4 as = a_s4[sidx];
        p0 = __expf(lrelu(as.x + ad.x) - m0);
        p1 = __expf(lrelu(as.y + ad.y) - m1);
        p2 = __expf(lrelu(as.z + ad.z) - m2);
        p3 = __expf(lrelu(as.w + ad.w) - m3);
      }
      s0 += wave_sum64(p0); s1 += wave_sum64(p1);
      s2 += wave_sum64(p2); s3 += wave_sum64(p3);
      pbuf[w][0][l] = p0; pbuf[w][1][l] = p1;
      pbuf[w][2][l] = p2; pbuf[w][3][l] = p3;
      for (int j = 0; j < cnt; ++j) {
        int tj = __builtin_amdgcn_readlane(sidx, j);
        float qj = pbuf[w][h][j];
        unsigned int u = xwu[(size_t)tj * 64 + l];
        a0[0] = fmaf(qj, FP8DEC(u, 0), a0[0]); a0[1] = fmaf(qj, FP8DEC(u, 1), a0[1]);
        a0[2] = fmaf(qj, FP8DEC(u, 2), a0[2]); a0[3] = fmaf(qj, FP8DEC(u, 3), a0[3]);
      }
    }
  }

  float smy = h == 0 ? s0 : h == 1 ? s1 : h == 2 ? s2 : s3;
  float inv = 1.f / smy;
  float4 bv = ((const float4*)bias)[l];
  float o0 = ((a0[0] + a1[0]) + (a2[0] + a3[0])) * inv + bv.x;
  float o1 = ((a0[1] + a1[1]) + (a2[1] + a3[1])) * inv + bv.y;
  float o2 = ((a0[2] + a1[2]) + (a2[2] + a3[2])) * inv + bv.z;
  float o3 = ((a0[3] + a1[3]) + (a2[3] + a3[3])) * inv + bv.w;
  if (ACT) {
    o0 = o0 > 0.f ? o0 : __expf(o0) - 1.f;
    o1 = o1 > 0.f ? o1 : __expf(o1) - 1.f;
    o2 = o2 > 0.f ? o2 : __expf(o2) - 1.f;
    o3 = o3 > 0.f ? o3 : __expf(o3) - 1.f;
  }
  ushort4 ov;
  ov.x = f2bf(o0); ov.y = f2bf(o1); ov.z = f2bf(o2); ov.w = f2bf(o3);
  ((ushort4*)(hout + (size_t)n * 256))[l] = ov;
}

// ---------------- fused softmax + aggregation, H=1 (fp8 rows, 64B) ----------------

template <int WPB>
__global__ __launch_bounds__(64 * WPB) void fagg1_k(
    const unsigned char* __restrict__ xw, const float* __restrict__ a_s,
    const float* __restrict__ a_d, const int* __restrict__ rowptr,
    const int* __restrict__ csr_src, const float* __restrict__ bias,
    float* __restrict__ hout, int N) {
  __shared__ float pbuf[WPB][64];
  __shared__ int sbuf[WPB][64];
  int w = threadIdx.x >> 6, l = threadIdx.x & 63;
  int n = blockIdx.x * WPB + w;
  if (n >= N) return;
  int g = l >> 4, q = l & 15;
  int beg = rowptr[n], end = rowptr[n + 1];
  int deg = end - beg;
  float ad = a_d[n];
  f32x4 acc = {0.f, 0.f, 0.f, 0.f};
  const unsigned int* xwu = (const unsigned int*)xw;
  float ss;

  if (deg <= 64) {
    int cnt = deg;
    float e = -1e30f;
    int sidx = 0;
    if (l < cnt) {
      sidx = csr_src[beg + l];
      e = lrelu(a_s[sidx] + ad);
    }
    float m = wave_max64(e);
    float p = __expf(e - m);
    ss = wave_sum64(p);
    pbuf[w][l] = p;
    sbuf[w][l] = sidx;
    for (int j = 0; j < cnt; j += 4) {
      int jj = j + g;
      bool ok = jj < cnt;
      int idx = ok ? jj : 0;
      float pj = ok ? pbuf[w][idx] : 0.f;
      int sj = sbuf[w][idx];
      unsigned int u = xwu[(size_t)sj * 16 + q];
      acc[0] = fmaf(pj, FP8DEC(u, 0), acc[0]);
      acc[1] = fmaf(pj, FP8DEC(u, 1), acc[1]);
      acc[2] = fmaf(pj, FP8DEC(u, 2), acc[2]);
      acc[3] = fmaf(pj, FP8DEC(u, 3), acc[3]);
    }
  } else {
    float m = -1e30f;
    for (int c0 = beg; c0 < end; c0 += 64) {
      int cnt = min(64, end - c0);
      float e = -1e30f;
      if (l < cnt) e = lrelu(a_s[csr_src[c0 + l]] + ad);
      m = fmaxf(m, wave_max64(e));
    }
    ss = 0.f;
    for (int c0 = beg; c0 < end; c0 += 64) {
      int cnt = min(64, end - c0);
      int sidx = 0;
      float p = 0.f;
      if (l < cnt) {
        sidx = csr_src[c0 + l];
        p = __expf(lrelu(a_s[sidx] + ad) - m);
      }
      ss += wave_sum64(p);
      pbuf[w][l] = p;
      sbuf[w][l] = sidx;
      for (int j = 0; j < cnt; j += 4) {
        int jj = j + g;
        bool ok = jj < cnt;
        int idx = ok ? jj : 0;
        float pj = ok ? pbuf[w][idx] : 0.f;
        int sj = sbuf[w][idx];
        unsigned int u = xwu[(size_t)sj * 16 + q];
        acc[0] = fmaf(pj, FP8DEC(u, 0), acc[0]);
        acc[1] = fmaf(pj, FP8DEC(u, 1), acc[1]);
        acc[2] = fmaf(pj, FP8DEC(u, 2), acc[2]);
        acc[3] = fmaf(pj, FP8DEC(u, 3), acc[3]);
      }
    }
  }
#pragma unroll
  for (int i = 0; i < 4; ++i) {
    acc[i] += __shfl_xor(acc[i], 16);
    acc[i] += __shfl_xor(acc[i], 32);
  }
  float inv = 1.f / ss;
  float4 bv = ((const float4*)bias)[q];
  float4 o;
  o.x = acc[0] * inv + bv.x;
  o.y = acc[1] * inv + bv.y;
  o.z = acc[2] * inv + bv.z;
  o.w = acc[3] * inv + bv.w;
  if (g == 0) ((float4*)(hout + (size_t)n * 64))[q] = o;
}

// ---------------- final mean over nodes + classifier ----------------

__global__ void reduce_mean_k(const float* __restrict__ h3, float* __restrict__ g, int N) {
  __shared__ float sm[4][64];
  int w = threadIdx.x >> 6;
  int lane = threadIdx.x & 63;
  float acc = 0.f;
  for (int n = blockIdx.x * 4 + w; n < N; n += gridDim.x * 4)
    acc += h3[(size_t)n * 64 + lane];
  sm[w][lane] = acc;
  __syncthreads();
  if (w == 0) {
    float t = sm[0][lane] + sm[1][lane] + sm[2][lane] + sm[3][lane];
    atomicAdd(&g[lane], t);
  }
}

__global__ void final_k(const float* __restrict__ g, const float* __restrict__ Wc,
                        const float* __restrict__ bc, float* __restrict__ out, int N) {
  int lane = threadIdx.x;  // 64
  float gc = g[lane] / (float)N;
  for (int j = 0; j < 10; ++j) {
    float v = gc * Wc[lane * 10 + j];
    for (int off = 32; off; off >>= 1) v += __shfl_down(v, off);
    if (lane == 0) out[j] = v + bc[j];
  }
}

// ---------------- launch ----------------

extern "C" void kernel_launch(void* const* d_in, const int* in_sizes, int n_in,
                              void* d_out, int out_size, void* d_ws, size_t ws_size,
                              hipStream_t stream) {
  const float* x   = (const float*)d_in[0];
  const int*   ei  = (const int*)d_in[1];
  const float* W1  = (const float*)d_in[2];
  const float* as1 = (const float*)d_in[3];
  const float* ad1 = (const float*)d_in[4];
  const float* b1  = (const float*)d_in[5];
  const float* W2  = (const float*)d_in[6];
  const float* as2 = (const float*)d_in[7];
  const float* ad2 = (const float*)d_in[8];
  const float* b2  = (const float*)d_in[9];
  const float* W3  = (const float*)d_in[10];
  const float* as3 = (const float*)d_in[11];
  const float* ad3 = (const float*)d_in[12];
  const float* b3  = (const float*)d_in[13];
  const float* Wc  = (const float*)d_in[14];
  const float* bc  = (const float*)d_in[15];
  float* out = (float*)d_out;

  int N = in_sizes[0] / 128;
  int E = in_sizes[1] / 2;
  int E2 = E + N;

  char* w = (char*)d_ws;
  auto alloc = [&](size_t bytes) {
    char* p = w;
    w += (bytes + 255) & ~(size_t)255;
    return p;
  };
  ushort* xb   = (ushort*)alloc((size_t)N * 128 * 2);  // reused as h3f (layer 3, f32[N][64])
  float*  h3f  = (float*)xb;
  unsigned char* xw8 = (unsigned char*)alloc((size_t)N * 256);  // fp8 gather table
  ushort* hb   = (ushort*)alloc((size_t)N * 256 * 2);
  ushort* w1t  = (ushort*)alloc((size_t)256 * 128 * 2);
  ushort* w2t  = (ushort*)alloc((size_t)256 * 256 * 2);
  ushort* w3t  = (ushort*)alloc((size_t)64 * 256 * 2);
  float*  a_s  = (float*)alloc((size_t)N * 4 * 4);
  float*  a_d  = (float*)alloc((size_t)N * 4 * 4);
  int*   deg    = (int*)alloc((size_t)N * 4);
  int*   excl   = (int*)alloc((size_t)N * 4);
  int*   bsum   = (int*)alloc(64 * 4);
  int*   rowptr = (int*)alloc((size_t)(N + 1) * 4);
  int*   eoff   = (int*)alloc((size_t)E2 * 4);
  int*   csr    = (int*)alloc((size_t)E2 * 4);
  float* g      = (float*)alloc(64 * 4);

  hipMemsetAsync(deg, 0, (size_t)N * 4, stream);
  hipMemsetAsync(g, 0, 64 * 4, stream);

  // conversions
  f2b_k<<<(N * 128 / 4 + 255) / 256, 256, 0, stream>>>(x, xb, N * 128 / 4);
  wtrans3_k<<<dim3(16, 16, 3), 256, 0, stream>>>(W1, W2, W3, w1t, w2t, w3t);

  // CSR
  int gE2 = (E2 + 255) / 256;
  histoff_k<<<gE2, 256, 0, stream>>>(ei, E, E2, deg, eoff);
  int nb = (N + 1023) / 1024;
  scan1_k<<<nb, 256, 0, stream>>>(deg, excl, bsum, N);
  scan2_k<<<1, 64, 0, stream>>>(bsum, nb);
  scan3_k<<<(N + 256) / 256, 256, 0, stream>>>(excl, bsum, rowptr, N, E2);
  scatter_k<<<gE2, 256, 0, stream>>>(ei, E, E2, rowptr, eoff, csr);

  int mb = (N + 127) / 128;
  int nwb = (N + 3) / 4;
  // layer 1
  gemm_att<<<dim3(4, mb), 256, 0, stream>>>(xb, w1t, xw8, as1, ad1, a_s, a_d, N, 256, 128, 4);
  fagg4_k<4, 1><<<nwb, 256, 0, stream>>>(xw8, (const float4*)a_s, (const float4*)a_d,
                                         rowptr, csr, b1, hb, N);
  // layer 2
  gemm_att<<<dim3(4, mb), 256, 0, stream>>>(hb, w2t, xw8, as2, ad2, a_s, a_d, N, 256, 256, 4);
  fagg4_k<4, 1><<<nwb, 256, 0, stream>>>(xw8, (const float4*)a_s, (const float4*)a_d,
                                         rowptr, csr, b2, hb, N);
  // layer 3 (single head)
  gemm_att<<<dim3(1, mb), 256, 0, stream>>>(hb, w3t, xw8, as3, ad3, a_s, a_d, N, 64, 256, 1);
  fagg1_k<4><<<nwb, 256, 0, stream>>>(xw8, a_s, a_d, rowptr, csr, b3, h3f, N);

  reduce_mean_k<<<256, 256, 0, stream>>>(h3f, g, N);
  final_k<<<1, 64, 0, stream>>>(g, Wc, bc, out, N);
}